// Round 7
// baseline (331.297 us; speedup 1.0000x reference)
//
#include <hip/hip_runtime.h>
#include <hip/hip_fp16.h>
#include <math.h>

#define BB   4
#define C_   128
#define H_   96
#define W_   192
#define COUT 128
#define DG_  2
#define CG_  64
#define K_   9
#define HO   96
#define WO   192
#define HW   (H_ * W_)       // 18432
#define OMCH 54
#define RDIM (C_ * K_)       // 1152
#define NKS  (RDIM / 32)     // 36 K-steps
#define NHALF 36864          // pixels per half (2 batches)

typedef __attribute__((ext_vector_type(8))) short bf16x8;
typedef __attribute__((ext_vector_type(4))) float f32x4;

struct __attribute__((packed, aligned(4))) fpair { float x, y; };

static __device__ __forceinline__ ushort f2bf(float f) {
  union { float f; uint u; } v; v.f = f;
  uint r = v.u + 0x7fff + ((v.u >> 16) & 1);   // RNE
  return (ushort)(r >> 16);
}

// ---------------------------------------------------------------------------
// Prep: bf16 weights, k-major orderings.
//  Wt [128][1152]  r' = g*576 + k*64 + cg   (so r'/32 = step, r'%32 = rk)
//  Awo[ 64][1152]  r''= k*128 + c, rows o'=g*32+j (j<27 real, else 0)
// ---------------------------------------------------------------------------
__global__ __launch_bounds__(256) void prep_k(
    const float* __restrict__ wd, const float* __restrict__ wo,
    ushort* __restrict__ Wt, ushort* __restrict__ Awo) {
  int i = blockIdx.x * 256 + threadIdx.x;
  if (i < 128 * RDIM) {
    int o = i / RDIM, r = i - o * RDIM;
    int g = r / 576, t = r - g * 576;
    int k = t >> 6, cg = t & 63;
    Wt[i] = f2bf(wd[((size_t)o * C_ + g * 64 + cg) * 9 + k]);
  }
  if (i < 64 * RDIM) {
    int o2 = i / RDIM, r = i - o2 * RDIM;
    int k = r >> 7, c = r & 127;
    int g = o2 >> 5, j = o2 & 31;
    float v = (((c >> 6) == g) && (j < 27))
                ? wo[(((size_t)(g * 27 + j)) * 64 + (c & 63)) * 9 + k] : 0.f;
    Awo[i] = f2bf(v);
  }
}

// ---------------------------------------------------------------------------
// Offset conv as MFMA (R3 exact — proven deterministic).
// ---------------------------------------------------------------------------
__global__ __launch_bounds__(256) void offset_mfma_k(
    const float* __restrict__ x, const ushort* __restrict__ Awo,
    const float* __restrict__ b_offset, float* __restrict__ om) {
  __shared__ uint s_val[2][64][20];

  int bid = blockIdx.x;
  int blk = (bid & 7) * 144 + (bid >> 3);
  int wt = blk % 3, bh = blk / 3;
  int ho = bh % HO, b = bh / HO;
  int wo0 = wt * 64;
  int lane = threadIdx.x & 63, wv = threadIdx.x >> 6;

  const float* xb = x + (size_t)b * C_ * HW;
  f32x4 acc[4];
#pragma unroll
  for (int n = 0; n < 4; ++n) acc[n] = (f32x4){0.f, 0.f, 0.f, 0.f};

  const ushort* abase = Awo + (size_t)(wv * 16 + (lane & 15)) * RDIM + (lane >> 4) * 8;

  float gv[8];

  auto patch_gather = [&](int step) {
    int k = step >> 2;
    int dy = k / 3, dx = k - dy * 3;
    int y  = ho - 2 + 2 * dy;
    int xc = wo0 + lane - 2 + 2 * dx;
    bool ok = (y >= 0) & (y < H_) & (xc >= 0) & (xc < W_);
    int c0 = (step & 3) * 32 + wv * 8;
    const float* pl = xb + ((ptrdiff_t)c0 * HW + y * W_ + xc);
#pragma unroll
    for (int j = 0; j < 8; ++j) { gv[j] = ok ? *pl : 0.f; pl += HW; }
  };

  auto patch_finish = [&](int nb) {
    uint res[4];
#pragma unroll
    for (int j = 0; j < 8; ++j) {
      uint bf = (uint)f2bf(gv[j]);
      if (j & 1) res[j >> 1] |= bf << 16; else res[j >> 1] = bf;
    }
    *(int4*)&s_val[nb][lane][wv * 4] = *(int4*)&res[0];
  };

  auto mfma_step = [&](int step, int cb) {
    bf16x8 af = *(const bf16x8*)(abase + step * 32);
#pragma unroll
    for (int n = 0; n < 4; ++n) {
      bf16x8 bfr = *(const bf16x8*)&s_val[cb][n * 16 + (lane & 15)][(lane >> 4) * 4];
      acc[n] = __builtin_amdgcn_mfma_f32_16x16x32_bf16(af, bfr, acc[n], 0, 0, 0);
    }
  };

  patch_gather(0);
  patch_finish(0);
  __syncthreads();
  for (int it = 0; it < NKS - 1; ++it) {
    patch_gather(it + 1);
    mfma_step(it, it & 1);
    patch_finish((it + 1) & 1);
    __syncthreads();
  }
  mfma_step(NKS - 1, (NKS - 1) & 1);

  int col = lane & 15, rgrp = lane >> 4;
#pragma unroll
  for (int n = 0; n < 4; ++n)
#pragma unroll
    for (int ri = 0; ri < 4; ++ri) {
      int o2 = wv * 16 + rgrp * 4 + ri;
      int g = o2 >> 5, j = o2 & 31;
      if (j < 27) {
        int ch = g * 27 + j;
        om[((size_t)(b * OMCH + ch) * HO + ho) * WO + wo0 + n * 16 + col] =
            acc[n][ri] + b_offset[ch];
      }
    }
}

// ---------------------------------------------------------------------------
// Coefficient phase (shared): canonical in-bounds bilinear, clamps folded
// into 4 f16 weights (exact in fp32; R6-proven math). 18 (g,k) x 64 px.
// ---------------------------------------------------------------------------
#define COEFF_PHASE_64(PXW)                                                    \
  for (int e = tid; e < 18 * 64; e += 256) {                                   \
    int p = e & 63, gk = e >> 6;                                               \
    int g = gk / 9, k = gk - g * 9;                                            \
    int wo = wo0 + p;                                                          \
    const float* omb = om + (size_t)b * OMCH * HW + (size_t)ho * WO + wo;      \
    float offy = omb[(size_t)(g * 18 + k * 2 + 0) * HW];                       \
    float offx = omb[(size_t)(g * 18 + k * 2 + 1) * HW];                       \
    float z    = omb[(size_t)(36 + g * 9 + k) * HW];                           \
    float msk  = 2.f / (1.f + __expf(-z));                                     \
    float py = (float)(ho - 2 + (k / 3) * 2) + offy;                           \
    float px = (float)(wo - 2 + (k % 3) * 2) + offx;                           \
    float y0f = floorf(py), x0f = floorf(px);                                  \
    int   y0 = (int)y0f, x0 = (int)x0f;                                        \
    float ty = py - y0f, tx = px - x0f;                                        \
    float wy0 = (y0 >= 0 && y0 < H_)      ? (1.f - ty) : 0.f;                  \
    float wy1 = (y0 >= -1 && y0 < H_ - 1) ? ty         : 0.f;                  \
    float wx0 = (x0 >= 0 && x0 < W_)      ? (1.f - tx) : 0.f;                  \
    float wx1 = (x0 >= -1 && x0 < W_ - 1) ? tx         : 0.f;                  \
    int yb  = min(max(y0, 0), H_ - 2);                                         \
    int xb_ = min(max(x0, 0), W_ - 2);                                         \
    float wAy = (y0 == yb      ? wy0 : 0.f) + (y0 + 1 == yb      ? wy1 : 0.f); \
    float wBy = (y0 == yb + 1  ? wy0 : 0.f) + (y0 + 1 == yb + 1  ? wy1 : 0.f); \
    float wAx = (x0 == xb_     ? wx0 : 0.f) + (x0 + 1 == xb_     ? wx1 : 0.f); \
    float wBx = (x0 == xb_ + 1 ? wx0 : 0.f) + (x0 + 1 == xb_ + 1 ? wx1 : 0.f); \
    s_addr[e] = (uint)(yb * W_ + xb_);                                         \
    union { __half2 h; uint u; } uA, uB;                                       \
    uA.h = __half2{__float2half(wAy * wAx * msk), __float2half(wAy * wBx * msk)}; \
    uB.h = __half2{__float2half(wBy * wAx * msk), __float2half(wBy * wBx * msk)}; \
    s_wq[e] = make_uint2(uA.u, uB.u);                                          \
  }

// ---------------------------------------------------------------------------
// Sampler: computes val and stores bf16 in B-fragment layout:
//   valB[((step*4 + oct)*NHALF + pxl)*8 + j]   (16 B per (thread,step), coalesced)
// Grid per half: 2 b x 288 px-tiles x 3 step-groups = 1728 blocks.
// No in-loop barriers; thread (lane=px, wv=oct) does 8 channels via 16 paired
// 8B loads sharing ONE coefficient.
// ---------------------------------------------------------------------------
__global__ __launch_bounds__(256) void sampler_k(
    int b0, const float* __restrict__ x, const float* __restrict__ om,
    ushort* __restrict__ valB) {
  __shared__ uint  s_addr[18 * 64];        // 4608 B
  __shared__ uint2 s_wq[18 * 64];          // 9216 B

  int bid = blockIdx.x;
  int blk = (bid & 7) * 216 + (bid >> 3);  // bijective, 1728 % 8 == 0
  int b_loc = blk / 864, rem = blk % 864;
  int sg = rem % 3, pt = rem / 3;          // pt 0..287
  int ho = pt / 3, wo0 = (pt % 3) * 64;
  int b = b0 + b_loc;
  int tid = threadIdx.x;
  int lane = tid & 63, wv = tid >> 6;

  COEFF_PHASE_64()
  __syncthreads();

  const float* xb = x + (size_t)b * C_ * HW;
  size_t pxl = (size_t)b_loc * 18432 + (size_t)ho * WO + wo0 + lane;

#pragma unroll 2
  for (int i = 0; i < 12; ++i) {
    int step = sg * 12 + i;
    int gg = step / 18, ks = step % 18;
    int k = ks >> 1, half = ks & 1;
    int ci = (gg * 9 + k) * 64 + lane;
    uint base = s_addr[ci];
    uint2 wq  = s_wq[ci];
    union { __half2 h; uint u; } uA, uB;
    uA.u = wq.x; uB.u = wq.y;
    float2 wA = __half22float2(uA.h);
    float2 wB = __half22float2(uB.h);
    const float* pl = xb + (size_t)(gg * 64 + half * 32 + wv * 8) * HW + base;
    float G[32];
#pragma unroll
    for (int j = 0; j < 8; ++j) {
      fpair top = *(const fpair*)(pl);
      fpair bot = *(const fpair*)(pl + W_);
      G[j] = top.x; G[8 + j] = top.y; G[16 + j] = bot.x; G[24 + j] = bot.y;
      pl += HW;
    }
    uint res[4];
#pragma unroll
    for (int j = 0; j < 8; ++j) {
      float v = wA.x * G[j] + wA.y * G[8 + j] + wB.x * G[16 + j] + wB.y * G[24 + j];
      uint bf = (uint)f2bf(v);
      if (j & 1) res[j >> 1] |= bf << 16; else res[j >> 1] = bf;
    }
    *(int4*)&valB[(((size_t)step * 4 + wv) * NHALF + pxl) * 8] = *(int4*)&res[0];
  }
}

// ---------------------------------------------------------------------------
// Streaming GEMM: no LDS, no barriers. Block = 64 px x 128 Cout, 4 waves.
// B-fragments loaded directly from valB (fragment-layout, coalesced dwordx4);
// A from Wt. Depth-2 register prefetch. 8 MFMA per step per wave.
// ---------------------------------------------------------------------------
__global__ __launch_bounds__(256) void gemm_k(
    int b0, const ushort* __restrict__ valB, const ushort* __restrict__ Wt,
    float* __restrict__ out) {
  int bid = blockIdx.x;
  int blk = (bid & 7) * 72 + (bid >> 3);   // bijective, 576 % 8 == 0
  int b_loc = blk / 288, pt = blk % 288;
  int ho = pt / 3, wo0 = (pt % 3) * 64;
  int b = b0 + b_loc;
  int lane = threadIdx.x & 63, wv = threadIdx.x >> 6;
  int col = lane & 15, oct = lane >> 4;

  const ushort* wb0 = Wt + (size_t)(wv * 32 + col) * RDIM + oct * 8;
  const ushort* wb1 = wb0 + (size_t)16 * RDIM;
  const ushort* vb  = valB + ((size_t)oct * NHALF
                    + (size_t)b_loc * 18432 + (size_t)ho * WO + wo0 + col) * 8;
  const size_t vstep = (size_t)4 * NHALF * 8;   // ushorts per step

  f32x4 acc[2][4];
#pragma unroll
  for (int m = 0; m < 2; ++m)
#pragma unroll
    for (int n = 0; n < 4; ++n) acc[m][n] = (f32x4){0.f, 0.f, 0.f, 0.f};

  // sets 0/1 for steps it2 / it2+1, refetched at distance 2
  bf16x8 a0_0, a1_0, b_0[4], a0_1, a1_1, b_1[4];
  a0_0 = *(const bf16x8*)(wb0);
  a1_0 = *(const bf16x8*)(wb1);
#pragma unroll
  for (int n = 0; n < 4; ++n) b_0[n] = *(const bf16x8*)(vb + n * 128);
  a0_1 = *(const bf16x8*)(wb0 + 32);
  a1_1 = *(const bf16x8*)(wb1 + 32);
#pragma unroll
  for (int n = 0; n < 4; ++n) b_1[n] = *(const bf16x8*)(vb + vstep + n * 128);

  for (int it2 = 0; it2 < NKS; it2 += 2) {
    {   // step it2 (set 0), prefetch it2+2 into set 0
      bf16x8 pa0 = a0_0, pa1 = a1_0, pb[4];
#pragma unroll
      for (int n = 0; n < 4; ++n) pb[n] = b_0[n];
      if (it2 + 2 < NKS) {
        a0_0 = *(const bf16x8*)(wb0 + (it2 + 2) * 32);
        a1_0 = *(const bf16x8*)(wb1 + (it2 + 2) * 32);
#pragma unroll
        for (int n = 0; n < 4; ++n)
          b_0[n] = *(const bf16x8*)(vb + (size_t)(it2 + 2) * vstep + n * 128);
      }
#pragma unroll
      for (int n = 0; n < 4; ++n) {
        acc[0][n] = __builtin_amdgcn_mfma_f32_16x16x32_bf16(pa0, pb[n], acc[0][n], 0, 0, 0);
        acc[1][n] = __builtin_amdgcn_mfma_f32_16x16x32_bf16(pa1, pb[n], acc[1][n], 0, 0, 0);
      }
    }
    {   // step it2+1 (set 1), prefetch it2+3 into set 1
      bf16x8 pa0 = a0_1, pa1 = a1_1, pb[4];
#pragma unroll
      for (int n = 0; n < 4; ++n) pb[n] = b_1[n];
      if (it2 + 3 < NKS) {
        a0_1 = *(const bf16x8*)(wb0 + (it2 + 3) * 32);
        a1_1 = *(const bf16x8*)(wb1 + (it2 + 3) * 32);
#pragma unroll
        for (int n = 0; n < 4; ++n)
          b_1[n] = *(const bf16x8*)(vb + (size_t)(it2 + 3) * vstep + n * 128);
      }
#pragma unroll
      for (int n = 0; n < 4; ++n) {
        acc[0][n] = __builtin_amdgcn_mfma_f32_16x16x32_bf16(pa0, pb[n], acc[0][n], 0, 0, 0);
        acc[1][n] = __builtin_amdgcn_mfma_f32_16x16x32_bf16(pa1, pb[n], acc[1][n], 0, 0, 0);
      }
    }
  }

  // epilogue: C/D col=lane&15, row=oct*4+reg
#pragma unroll
  for (int m = 0; m < 2; ++m)
#pragma unroll
    for (int n = 0; n < 4; ++n)
#pragma unroll
      for (int ri = 0; ri < 4; ++ri) {
        int o = wv * 32 + m * 16 + oct * 4 + ri;
        out[((size_t)(b * COUT + o) * HO + ho) * WO + wo0 + n * 16 + col] = acc[m][n][ri];
      }
}

// ---------------------------------------------------------------------------
// Fallback fused kernel (R6 exact — proven): used when ws_size is too small.
// ---------------------------------------------------------------------------
__global__ __launch_bounds__(256) void deform_main_k(
    const float* __restrict__ x, const float* __restrict__ om,
    const ushort* __restrict__ Wt, float* __restrict__ out) {
  __shared__ uint  s_addr[18 * 64];
  __shared__ uint2 s_wq[18 * 64];
  __shared__ uint  s_val[3][32][20];

  int bid = blockIdx.x;
  int blk = (bid & 7) * 288 + (bid >> 3);
  int wt = blk % 6, bh = blk / 6;
  int ho = bh % HO, b = bh / HO;
  int wo0 = wt * 32;
  int tid = threadIdx.x;
  int lane = tid & 63, wv = tid >> 6;

  for (int e = tid; e < 18 * 32; e += 256) {
    int p = e & 31, gk = e >> 5;
    int g = gk / 9, k = gk - g * 9;
    int wo = wo0 + p;
    const float* omb = om + (size_t)b * OMCH * HW + (size_t)ho * WO + wo;
    float offy = omb[(size_t)(g * 18 + k * 2 + 0) * HW];
    float offx = omb[(size_t)(g * 18 + k * 2 + 1) * HW];
    float z    = omb[(size_t)(36 + g * 9 + k) * HW];
    float msk  = 2.f / (1.f + __expf(-z));
    float py = (float)(ho - 2 + (k / 3) * 2) + offy;
    float px = (float)(wo - 2 + (k % 3) * 2) + offx;
    float y0f = floorf(py), x0f = floorf(px);
    int   y0 = (int)y0f, x0 = (int)x0f;
    float ty = py - y0f, tx = px - x0f;
    float wy0 = (y0 >= 0 && y0 < H_)      ? (1.f - ty) : 0.f;
    float wy1 = (y0 >= -1 && y0 < H_ - 1) ? ty         : 0.f;
    float wx0 = (x0 >= 0 && x0 < W_)      ? (1.f - tx) : 0.f;
    float wx1 = (x0 >= -1 && x0 < W_ - 1) ? tx         : 0.f;
    int yb  = min(max(y0, 0), H_ - 2);
    int xb_ = min(max(x0, 0), W_ - 2);
    float wAy = (y0 == yb      ? wy0 : 0.f) + (y0 + 1 == yb      ? wy1 : 0.f);
    float wBy = (y0 == yb + 1  ? wy0 : 0.f) + (y0 + 1 == yb + 1  ? wy1 : 0.f);
    float wAx = (x0 == xb_     ? wx0 : 0.f) + (x0 + 1 == xb_     ? wx1 : 0.f);
    float wBx = (x0 == xb_ + 1 ? wx0 : 0.f) + (x0 + 1 == xb_ + 1 ? wx1 : 0.f);
    s_addr[e] = (uint)(yb * W_ + xb_);
    union { __half2 h; uint u; } uA, uB;
    uA.h = __half2{__float2half(wAy * wAx * msk), __float2half(wAy * wBx * msk)};
    uB.h = __half2{__float2half(wBy * wAx * msk), __float2half(wBy * wBx * msk)};
    s_wq[e] = make_uint2(uA.u, uB.u);
  }

  const float* xb = x + (size_t)b * C_ * HW;
  int p = lane & 31;
  int s = (wv << 1) | (lane >> 5);

  f32x4 acc[2][2];
#pragma unroll
  for (int m = 0; m < 2; ++m)
#pragma unroll
    for (int n = 0; n < 2; ++n) acc[m][n] = (f32x4){0.f, 0.f, 0.f, 0.f};

  const ushort* wb0 = Wt + (size_t)(wv * 32 + (lane & 15)) * RDIM + (lane >> 4) * 8;
  const ushort* wb1 = wb0 + (size_t)16 * RDIM;

  float GA[16], GB[16];
  float4 wgA, wgB;

  auto val_gather = [&](int step, float (&G)[16], float4& wg) {
    int gg = step >= 18;
    int ks = step - (gg ? 18 : 0);
    int k  = ks >> 1, half = ks & 1;
    int ci = (gg * 9 + k) * 32 + p;
    uint base = s_addr[ci];
    uint2 wq  = s_wq[ci];
    union { __half2 h; uint u; } uA, uB;
    uA.u = wq.x; uB.u = wq.y;
    float2 wA = __half22float2(uA.h);
    float2 wB = __half22float2(uB.h);
    wg = make_float4(wA.x, wA.y, wB.x, wB.y);
    int c0 = gg * 64 + half * 32 + s * 4;
    const float* pl = xb + (size_t)c0 * HW + base;
#pragma unroll
    for (int j = 0; j < 4; ++j) {
      fpair top = *(const fpair*)(pl);
      fpair bot = *(const fpair*)(pl + W_);
      G[j] = top.x; G[4 + j] = top.y; G[8 + j] = bot.x; G[12 + j] = bot.y;
      pl += HW;
    }
  };

  auto val_finish = [&](const float (&G)[16], float4 wg, int nb) {
    uint res[2];
#pragma unroll
    for (int j = 0; j < 4; ++j) {
      float v = wg.x * G[j] + wg.y * G[4 + j] + wg.z * G[8 + j] + wg.w * G[12 + j];
      uint bf = (uint)f2bf(v);
      if (j & 1) res[j >> 1] |= bf << 16; else res[j >> 1] = bf;
    }
    *(uint2*)&s_val[nb][p][s * 2] = make_uint2(res[0], res[1]);
  };

  auto mfma_step = [&](int cb, bf16x8 a0, bf16x8 a1) {
#pragma unroll
    for (int n = 0; n < 2; ++n) {
      bf16x8 bfr = *(const bf16x8*)&s_val[cb][n * 16 + (lane & 15)][(lane >> 4) * 4];
      acc[0][n] = __builtin_amdgcn_mfma_f32_16x16x32_bf16(a0, bfr, acc[0][n], 0, 0, 0);
      acc[1][n] = __builtin_amdgcn_mfma_f32_16x16x32_bf16(a1, bfr, acc[1][n], 0, 0, 0);
    }
  };

  __syncthreads();
  val_gather(0, GA, wgA);
  val_finish(GA, wgA, 0);
  val_gather(1, GB, wgB);
  bf16x8 a0c = *(const bf16x8*)(wb0);
  bf16x8 a1c = *(const bf16x8*)(wb1);
  __syncthreads();

#pragma unroll 6
  for (int it = 0; it < NKS; ++it) {
    if (it + 2 < NKS) {
      if ((it & 1) == 0) val_gather(it + 2, GA, wgA);
      else               val_gather(it + 2, GB, wgB);
    }
    bf16x8 a0n = a0c, a1n = a1c;
    if (it + 1 < NKS) {
      a0n = *(const bf16x8*)(wb0 + (it + 1) * 32);
      a1n = *(const bf16x8*)(wb1 + (it + 1) * 32);
    }
    mfma_step(it % 3, a0c, a1c);
    if (it + 1 < NKS) {
      if ((it & 1) == 0) val_finish(GB, wgB, (it + 1) % 3);
      else               val_finish(GA, wgA, (it + 1) % 3);
    }
    __syncthreads();
    a0c = a0n; a1c = a1n;
  }

  int col = lane & 15, rgrp = lane >> 4;
#pragma unroll
  for (int m = 0; m < 2; ++m)
#pragma unroll
    for (int n = 0; n < 2; ++n)
#pragma unroll
      for (int ri = 0; ri < 4; ++ri) {
        int o = wv * 32 + m * 16 + rgrp * 4 + ri;
        out[((size_t)(b * COUT + o) * HO + ho) * WO + wo0 + n * 16 + col] = acc[m][n][ri];
      }
}

// ---------------------------------------------------------------------------
extern "C" void kernel_launch(void* const* d_in, const int* in_sizes, int n_in,
                              void* d_out, int out_size, void* d_ws, size_t ws_size,
                              hipStream_t stream) {
  const float* x        = (const float*)d_in[0];
  const float* w_offset = (const float*)d_in[1];
  const float* b_offset = (const float*)d_in[2];
  const float* w_deform = (const float*)d_in[3];
  float* out = (float*)d_out;

  char* ws = (char*)d_ws;
  float*  om   = (float*)ws;                            // 15,925,248 B
  ushort* Wt   = (ushort*)(ws + 15925248);              //    294,912 B
  ushort* Awo  = (ushort*)(ws + 15925248 + 294912);     //    147,456 B
  ushort* valB = (ushort*)(ws + 15925248 + 294912 + 147456);  // 84,934,656 B
  const size_t NEED = 15925248ull + 294912 + 147456 + 84934656;  // 101.3 MB

  prep_k<<<576, 256, 0, stream>>>(w_deform, w_offset, Wt, Awo);
  offset_mfma_k<<<1152, 256, 0, stream>>>(x, Awo, b_offset, om);

  if (ws_size >= NEED) {
    for (int h = 0; h < 2; ++h) {
      sampler_k<<<1728, 256, 0, stream>>>(h * 2, x, om, valB);
      gemm_k<<<576, 256, 0, stream>>>(h * 2, valB, Wt, out);
    }
  } else {
    deform_main_k<<<2304, 256, 0, stream>>>(x, om, Wt, out);
  }
}

// Round 8
// 327.919 us; speedup vs baseline: 1.0103x; 1.0103x over previous
//
#include <hip/hip_runtime.h>
#include <hip/hip_fp16.h>
#include <math.h>

#define BB   4
#define C_   128
#define H_   96
#define W_   192
#define COUT 128
#define DG_  2
#define CG_  64
#define K_   9
#define HO   96
#define WO   192
#define HW   (H_ * W_)       // 18432
#define OMCH 54
#define RDIM (C_ * K_)       // 1152
#define NKS  (RDIM / 32)     // 36 K-steps

typedef __attribute__((ext_vector_type(8))) short bf16x8;
typedef __attribute__((ext_vector_type(4))) float f32x4;

struct __attribute__((packed, aligned(4))) fpair { float x, y; };

static __device__ __forceinline__ ushort f2bf(float f) {
  union { float f; uint u; } v; v.f = f;
  uint r = v.u + 0x7fff + ((v.u >> 16) & 1);   // RNE
  return (ushort)(r >> 16);
}

// ---------------------------------------------------------------------------
// Prep: bf16 weights, k-major orderings (proven).
//  Wt [128][1152]  r' = g*576 + k*64 + cg
//  Awo[ 64][1152]  r''= k*128 + c, rows o'=g*32+j (j<27 real, else 0)
// ---------------------------------------------------------------------------
__global__ __launch_bounds__(256) void prep_k(
    const float* __restrict__ wd, const float* __restrict__ wo,
    ushort* __restrict__ Wt, ushort* __restrict__ Awo) {
  int i = blockIdx.x * 256 + threadIdx.x;
  if (i < 128 * RDIM) {
    int o = i / RDIM, r = i - o * RDIM;
    int g = r / 576, t = r - g * 576;
    int k = t >> 6, cg = t & 63;
    Wt[i] = f2bf(wd[((size_t)o * C_ + g * 64 + cg) * 9 + k]);
  }
  if (i < 64 * RDIM) {
    int o2 = i / RDIM, r = i - o2 * RDIM;
    int k = r >> 7, c = r & 127;
    int g = o2 >> 5, j = o2 & 31;
    float v = (((c >> 6) == g) && (j < 27))
                ? wo[(((size_t)(g * 27 + j)) * 64 + (c & 63)) * 9 + k] : 0.f;
    Awo[i] = f2bf(v);
  }
}

// ---------------------------------------------------------------------------
// Offset conv as MFMA (R3 exact — proven deterministic).
// ---------------------------------------------------------------------------
__global__ __launch_bounds__(256) void offset_mfma_k(
    const float* __restrict__ x, const ushort* __restrict__ Awo,
    const float* __restrict__ b_offset, float* __restrict__ om) {
  __shared__ uint s_val[2][64][20];

  int bid = blockIdx.x;
  int blk = (bid & 7) * 144 + (bid >> 3);
  int wt = blk % 3, bh = blk / 3;
  int ho = bh % HO, b = bh / HO;
  int wo0 = wt * 64;
  int lane = threadIdx.x & 63, wv = threadIdx.x >> 6;

  const float* xb = x + (size_t)b * C_ * HW;
  f32x4 acc[4];
#pragma unroll
  for (int n = 0; n < 4; ++n) acc[n] = (f32x4){0.f, 0.f, 0.f, 0.f};

  const ushort* abase = Awo + (size_t)(wv * 16 + (lane & 15)) * RDIM + (lane >> 4) * 8;

  float gv[8];

  auto patch_gather = [&](int step) {
    int k = step >> 2;
    int dy = k / 3, dx = k - dy * 3;
    int y  = ho - 2 + 2 * dy;
    int xc = wo0 + lane - 2 + 2 * dx;
    bool ok = (y >= 0) & (y < H_) & (xc >= 0) & (xc < W_);
    int c0 = (step & 3) * 32 + wv * 8;
    const float* pl = xb + ((ptrdiff_t)c0 * HW + y * W_ + xc);
#pragma unroll
    for (int j = 0; j < 8; ++j) { gv[j] = ok ? *pl : 0.f; pl += HW; }
  };

  auto patch_finish = [&](int nb) {
    uint res[4];
#pragma unroll
    for (int j = 0; j < 8; ++j) {
      uint bf = (uint)f2bf(gv[j]);
      if (j & 1) res[j >> 1] |= bf << 16; else res[j >> 1] = bf;
    }
    *(int4*)&s_val[nb][lane][wv * 4] = *(int4*)&res[0];
  };

  auto mfma_step = [&](int step, int cb) {
    bf16x8 af = *(const bf16x8*)(abase + step * 32);
#pragma unroll
    for (int n = 0; n < 4; ++n) {
      bf16x8 bfr = *(const bf16x8*)&s_val[cb][n * 16 + (lane & 15)][(lane >> 4) * 4];
      acc[n] = __builtin_amdgcn_mfma_f32_16x16x32_bf16(af, bfr, acc[n], 0, 0, 0);
    }
  };

  patch_gather(0);
  patch_finish(0);
  __syncthreads();
  for (int it = 0; it < NKS - 1; ++it) {
    patch_gather(it + 1);
    mfma_step(it, it & 1);
    patch_finish((it + 1) & 1);
    __syncthreads();
  }
  mfma_step(NKS - 1, (NKS - 1) & 1);

  int col = lane & 15, rgrp = lane >> 4;
#pragma unroll
  for (int n = 0; n < 4; ++n)
#pragma unroll
    for (int ri = 0; ri < 4; ++ri) {
      int o2 = wv * 16 + rgrp * 4 + ri;
      int g = o2 >> 5, j = o2 & 31;
      if (j < 27) {
        int ch = g * 27 + j;
        om[((size_t)(b * OMCH + ch) * HO + ho) * WO + wo0 + n * 16 + col] =
            acc[n][ri] + b_offset[ch];
      }
    }
}

// ---------------------------------------------------------------------------
// Tile-fused main kernel. Block = 16 px x 128 Cout, 4608 blocks, 2 barriers.
// Phase 1 (barrier-free): 256 threads = 16 px x 16 r-slots; thread samples
//   2 vals/step x 36 steps into LDS s_val[step][px][rk] (B-frag layout).
// Phase 2: 4 waves x 72 MFMA; B from LDS (16B/lane, conflict-free), A from
//   L2-hot Wt with depth-2 register prefetch.
// ---------------------------------------------------------------------------
__global__ __launch_bounds__(256) void deform_tile_k(
    const float* __restrict__ x, const float* __restrict__ om,
    const ushort* __restrict__ Wt, float* __restrict__ out) {
  __shared__ uint  s_addr[288];            // 1152 B: [gk][px] base addr
  __shared__ uint2 s_wq[288];              // 2304 B: 4 x f16 folded weights
  __shared__ uint  s_val[NKS * 16 * 16];   // 36864 B: [step][px][rk/2] uints

  int bid = blockIdx.x;
  int blk = (bid & 7) * 576 + (bid >> 3);  // bijective, 4608 % 8 == 0
  int pt = blk % 1152, b = blk / 1152;
  int ho = pt / 12, wo0 = (pt % 12) * 16;
  int tid = threadIdx.x;

  // ---- phase 0: canonical in-bounds bilinear coefficients, 18 gk x 16 px ----
  for (int e = tid; e < 288; e += 256) {
    int px = e & 15, gk = e >> 4;
    int g = gk / 9, k = gk - g * 9;
    int wo = wo0 + px;
    const float* omb = om + (size_t)b * OMCH * HW + (size_t)ho * WO + wo;
    float offy = omb[(size_t)(g * 18 + k * 2 + 0) * HW];
    float offx = omb[(size_t)(g * 18 + k * 2 + 1) * HW];
    float z    = omb[(size_t)(36 + g * 9 + k) * HW];
    float msk  = 2.f / (1.f + __expf(-z));
    float py = (float)(ho - 2 + (k / 3) * 2) + offy;
    float px_ = (float)(wo - 2 + (k % 3) * 2) + offx;
    float y0f = floorf(py), x0f = floorf(px_);
    int   y0 = (int)y0f, x0 = (int)x0f;
    float ty = py - y0f, tx = px_ - x0f;
    float wy0 = (y0 >= 0 && y0 < H_)      ? (1.f - ty) : 0.f;
    float wy1 = (y0 >= -1 && y0 < H_ - 1) ? ty         : 0.f;
    float wx0 = (x0 >= 0 && x0 < W_)      ? (1.f - tx) : 0.f;
    float wx1 = (x0 >= -1 && x0 < W_ - 1) ? tx         : 0.f;
    int yb  = min(max(y0, 0), H_ - 2);
    int xb_ = min(max(x0, 0), W_ - 2);
    float wAy = (y0 == yb      ? wy0 : 0.f) + (y0 + 1 == yb      ? wy1 : 0.f);
    float wBy = (y0 == yb + 1  ? wy0 : 0.f) + (y0 + 1 == yb + 1  ? wy1 : 0.f);
    float wAx = (x0 == xb_     ? wx0 : 0.f) + (x0 + 1 == xb_     ? wx1 : 0.f);
    float wBx = (x0 == xb_ + 1 ? wx0 : 0.f) + (x0 + 1 == xb_ + 1 ? wx1 : 0.f);
    s_addr[e] = (uint)(yb * W_ + xb_);
    union { __half2 h; uint u; } uA, uB;
    uA.h = __half2{__float2half(wAy * wAx * msk), __float2half(wAy * wBx * msk)};
    uB.h = __half2{__float2half(wBy * wAx * msk), __float2half(wBy * wBx * msk)};
    s_wq[e] = make_uint2(uA.u, uB.u);
  }
  __syncthreads();

  // ---- phase 1: sample 1152 r x 16 px into LDS (no barriers) ----
  {
    int s = tid >> 4, px = tid & 15;     // r-slot, pixel
    const float* xb = x + (size_t)b * C_ * HW;
#pragma unroll 3
    for (int step = 0; step < NKS; ++step) {
      int g = step / 18, ks = step % 18;
      int k = ks >> 1, half = ks & 1;
      int ci = (g * 9 + k) * 16 + px;
      uint base = s_addr[ci];
      uint2 wq  = s_wq[ci];
      union { __half2 h; uint u; } uA, uB;
      uA.u = wq.x; uB.u = wq.y;
      float2 wA = __half22float2(uA.h);
      float2 wB = __half22float2(uB.h);
      const float* pl0 = xb + (size_t)(g * 64 + half * 32 + s * 2) * HW + base;
      const float* pl1 = pl0 + HW;
      fpair t0 = *(const fpair*)(pl0);
      fpair b0 = *(const fpair*)(pl0 + W_);
      fpair t1 = *(const fpair*)(pl1);
      fpair b1 = *(const fpair*)(pl1 + W_);
      float v0 = wA.x * t0.x + wA.y * t0.y + wB.x * b0.x + wB.y * b0.y;
      float v1 = wA.x * t1.x + wA.y * t1.y + wB.x * b1.x + wB.y * b1.y;
      s_val[(step * 16 + px) * 16 + s] = (uint)f2bf(v0) | ((uint)f2bf(v1) << 16);
    }
  }
  __syncthreads();

  // ---- phase 2: GEMM from LDS ----
  int lane = tid & 63, wv = tid >> 6;
  int col = lane & 15, oct = lane >> 4;

  const ushort* wb0 = Wt + (size_t)(wv * 32 + col) * RDIM + oct * 8;
  const ushort* wb1 = wb0 + (size_t)16 * RDIM;

  f32x4 acc[2];
  acc[0] = (f32x4){0.f, 0.f, 0.f, 0.f};
  acc[1] = (f32x4){0.f, 0.f, 0.f, 0.f};

  bf16x8 a0_0 = *(const bf16x8*)(wb0);
  bf16x8 a1_0 = *(const bf16x8*)(wb1);
  bf16x8 a0_1 = *(const bf16x8*)(wb0 + 32);
  bf16x8 a1_1 = *(const bf16x8*)(wb1 + 32);

  for (int it2 = 0; it2 < NKS; it2 += 2) {
    {
      bf16x8 pa0 = a0_0, pa1 = a1_0;
      if (it2 + 2 < NKS) {
        a0_0 = *(const bf16x8*)(wb0 + (it2 + 2) * 32);
        a1_0 = *(const bf16x8*)(wb1 + (it2 + 2) * 32);
      }
      bf16x8 bfr = *(const bf16x8*)&s_val[(it2 * 16 + col) * 16 + oct * 4];
      acc[0] = __builtin_amdgcn_mfma_f32_16x16x32_bf16(pa0, bfr, acc[0], 0, 0, 0);
      acc[1] = __builtin_amdgcn_mfma_f32_16x16x32_bf16(pa1, bfr, acc[1], 0, 0, 0);
    }
    {
      bf16x8 pa0 = a0_1, pa1 = a1_1;
      if (it2 + 3 < NKS) {
        a0_1 = *(const bf16x8*)(wb0 + (it2 + 3) * 32);
        a1_1 = *(const bf16x8*)(wb1 + (it2 + 3) * 32);
      }
      bf16x8 bfr = *(const bf16x8*)&s_val[((it2 + 1) * 16 + col) * 16 + oct * 4];
      acc[0] = __builtin_amdgcn_mfma_f32_16x16x32_bf16(pa0, bfr, acc[0], 0, 0, 0);
      acc[1] = __builtin_amdgcn_mfma_f32_16x16x32_bf16(pa1, bfr, acc[1], 0, 0, 0);
    }
  }

  // epilogue: C/D col=lane&15 (px), row=oct*4+reg (Cout)
#pragma unroll
  for (int m = 0; m < 2; ++m)
#pragma unroll
    for (int ri = 0; ri < 4; ++ri) {
      int o = wv * 32 + m * 16 + oct * 4 + ri;
      out[((size_t)(b * COUT + o) * HO + ho) * WO + wo0 + col] = acc[m][ri];
    }
}

// ---------------------------------------------------------------------------
extern "C" void kernel_launch(void* const* d_in, const int* in_sizes, int n_in,
                              void* d_out, int out_size, void* d_ws, size_t ws_size,
                              hipStream_t stream) {
  const float* x        = (const float*)d_in[0];
  const float* w_offset = (const float*)d_in[1];
  const float* b_offset = (const float*)d_in[2];
  const float* w_deform = (const float*)d_in[3];
  float* out = (float*)d_out;

  char* ws = (char*)d_ws;
  float*  om  = (float*)ws;                           // 15,925,248 B
  ushort* Wt  = (ushort*)(ws + 15925248);             //    294,912 B
  ushort* Awo = (ushort*)(ws + 15925248 + 294912);    //    147,456 B

  prep_k<<<576, 256, 0, stream>>>(w_deform, w_offset, Wt, Awo);
  offset_mfma_k<<<1152, 256, 0, stream>>>(x, Awo, b_offset, om);
  deform_tile_k<<<4608, 256, 0, stream>>>(x, om, Wt, out);
}